// Round 15
// baseline (35674.188 us; speedup 1.0000x reference)
//
#include <hip/hip_runtime.h>
#include <cstdint>

#define T_STEPS 8192
#define HDIM    1024
#define NBLK    256
#define NTHR    256

typedef float        f32x4 __attribute__((ext_vector_type(4)));
typedef unsigned int u32x4 __attribute__((ext_vector_type(4)));

__device__ __forceinline__ float dot4(f32x4 a, f32x4 b) {
    return a[0] * b[0] + a[1] * b[1] + a[2] * b[2] + a[3] * b[3];
}
__device__ __forceinline__ float sigmoidf_(float v) { return 1.0f / (1.0f + __expf(-v)); }
__device__ __forceinline__ float tanhf_(float v)    { return 1.0f - 2.0f / (__expf(2.0f * v) + 1.0f); }
__device__ __forceinline__ unsigned bf16_rne(float f) {
    unsigned b = __float_as_uint(f);
    return (b + 0x7FFFu + ((b >> 16) & 1u)) >> 16;
}

// lgkm-only barrier: LDS visibility without draining vmcnt — the post-detect
// x prefetch stays in flight across the step boundary (proven R13/R14).
#define BAR() do {                                            \
    asm volatile("s_waitcnt lgkmcnt(0)" ::: "memory");        \
    __builtin_amdgcn_sched_barrier(0);                        \
    __builtin_amdgcn_s_barrier();                             \
    __builtin_amdgcn_sched_barrier(0);                        \
} while (0)

// One LSTM step. Order (the point of R15): publish -> gxp filler ->
// poll-late (R8's proven fresh-check; its vmcnt(0) now drains ONLY the
// publish ack) -> stag store (block-PRIVATE line; out[] had 4 writer CUs
// per 64B line = R7's ping-pong, 10x WRITE amplification) -> x prefetch
// (crosses BAR in flight; retires before next step's filler uses it).
#define STEP_BODY(T_, XR_, XN_)                                               \
{                                                                             \
    const int t_ = (T_);                                                      \
    float acc[4];                                                             \
    _Pragma("unroll")                                                         \
    for (int q = 0; q < 4; ++q) {                                             \
        float a = gxp[q];                                                     \
        _Pragma("unroll")                                                     \
        for (int i = 0; i < 4; ++i) a += dot4(whh[q * 4 + i], hr[i]);         \
        acc[q] = a;                                                           \
    }                                                                         \
    _Pragma("unroll")                                                         \
    for (int m = 1; m < 64; m <<= 1) {                                        \
        _Pragma("unroll")                                                     \
        for (int q = 0; q < 4; ++q) acc[q] += __shfl_xor(acc[q], m, 64);      \
    }                                                                         \
    const float gi = sigmoidf_(acc[0] + bias[0]);                             \
    const float gf = sigmoidf_(acc[1] + bias[1]);                             \
    const float gg = tanhf_   (acc[2] + bias[2]);                             \
    const float go = sigmoidf_(acc[3] + bias[3]);                             \
    c = gf * c + gi * gg;                                                     \
    const float hval = go * tanhf_(c);                                        \
    if (l == 0) {                                                             \
        const unsigned pk = ((unsigned)(t_ + 1) << 16) | bf16_rne(hval);      \
        unsigned int* slot = ring + (((t_ & 1) * NBLK + blockIdx.x) << 4) + w;\
        asm volatile("global_store_dword %0, %1, off sc0 sc1"                 \
                     :: "v"((unsigned long long)slot), "v"(pk) : "memory");   \
    }                                                                         \
    _Pragma("unroll")                                                         \
    for (int q = 0; q < 4; ++q) {                                             \
        float a = 0.f;                                                        \
        _Pragma("unroll")                                                     \
        for (int i = 0; i < 4; ++i) a += dot4(wih[q * 4 + i], XR_[i]);        \
        gxp[q] = a;                                                           \
    }                                                                         \
    {                                                                         \
        const unsigned e = (unsigned)(t_ + 1);                                \
        const unsigned long long base =                                       \
            (unsigned long long)(ring + (((t_ & 1) * NBLK + tid) << 4));      \
        u32x4 p;                                                              \
        for (;;) {                                                            \
            asm volatile("global_load_dwordx4 %0, %1, off sc0 sc1\n\t"        \
                         "s_waitcnt vmcnt(0)"                                 \
                         : "=&v"(p) : "v"(base) : "memory");                  \
            if ((p[0] >> 16) == e && (p[1] >> 16) == e &&                     \
                (p[2] >> 16) == e && (p[3] >> 16) == e) break;                \
        }                                                                     \
        const int ns = (t_ + 1) & 1;                                          \
        f32x4 hv;                                                             \
        hv[0] = __uint_as_float(p[0] << 16);                                  \
        hv[1] = __uint_as_float(p[1] << 16);                                  \
        hv[2] = __uint_as_float(p[2] << 16);                                  \
        hv[3] = __uint_as_float(p[3] << 16);                                  \
        *(f32x4*)&h_lds[ns][4 * tid] = hv;                                    \
    }                                                                         \
    if (l == 0) stagb[t_ * 4 + w] = hval;                                     \
    {                                                                         \
        const int tn = (t_ + 2 < T_STEPS) ? (t_ + 2) : (T_STEPS - 1);         \
        const float* xp = x + (size_t)tn * HDIM;                              \
        _Pragma("unroll")                                                     \
        for (int i = 0; i < 4; ++i)                                           \
            XN_[i] = *(const f32x4*)(xp + 4 * l + 256 * i);                   \
    }                                                                         \
    BAR();                                                                    \
    {                                                                         \
        const int ns = (t_ + 1) & 1;                                          \
        _Pragma("unroll")                                                     \
        for (int i = 0; i < 4; ++i)                                           \
            hr[i] = *(const f32x4*)&h_lds[ns][4 * l + 256 * i];               \
    }                                                                         \
}

__global__ __launch_bounds__(NTHR, 1)
void lstm_persistent(const float* __restrict__ x,
                     const float* __restrict__ W_ih,
                     const float* __restrict__ W_hh,
                     const float* __restrict__ b_ih,
                     const float* __restrict__ b_hh,
                     const float* __restrict__ h0,
                     const float* __restrict__ c0,
                     float* __restrict__ stag,
                     unsigned int* __restrict__ ring)
{
    __shared__ float h_lds[2][HDIM];

    const int tid = threadIdx.x;
    const int w   = tid >> 6;   // wave 0..3
    const int l   = tid & 63;   // lane
    const int u   = (blockIdx.x << 2) + w;

    f32x4 whh[16], wih[16];
#pragma unroll
    for (int q = 0; q < 4; ++q) {
        const float* rh = W_hh + (size_t)(q * HDIM + u) * HDIM + 4 * l;
        const float* ri = W_ih + (size_t)(q * HDIM + u) * HDIM + 4 * l;
#pragma unroll
        for (int i = 0; i < 4; ++i) {
            whh[q * 4 + i] = *(const f32x4*)(rh + 256 * i);
            wih[q * 4 + i] = *(const f32x4*)(ri + 256 * i);
        }
    }
#pragma unroll
    for (int k = 0; k < 16; ++k) {
        asm volatile("" : "+v"(whh[k]));
        asm volatile("" : "+v"(wih[k]));
    }

    float bias[4];
#pragma unroll
    for (int q = 0; q < 4; ++q) bias[q] = b_ih[q * HDIM + u] + b_hh[q * HDIM + u];
    float c = c0[u];

    f32x4 hr[4];
#pragma unroll
    for (int i = 0; i < 4; ++i) hr[i] = *(const f32x4*)(h0 + 4 * l + 256 * i);

    float gxp[4];
    {
        f32x4 x0[4];
#pragma unroll
        for (int i = 0; i < 4; ++i) x0[i] = *(const f32x4*)(x + 4 * l + 256 * i);
#pragma unroll
        for (int q = 0; q < 4; ++q) {
            float a = 0.f;
#pragma unroll
            for (int i = 0; i < 4; ++i) a += dot4(wih[q * 4 + i], x0[i]);
            gxp[q] = a;
        }
    }
    f32x4 xA[4], xB[4];
#pragma unroll
    for (int i = 0; i < 4; ++i) xA[i] = *(const f32x4*)(x + HDIM + 4 * l + 256 * i);

    float* stagb = stag + (size_t)blockIdx.x * T_STEPS * 4;

    for (int t2 = 0; t2 < T_STEPS; t2 += 2) {
        STEP_BODY(t2, xA, xB);              // even step: never last
        if (t2 + 1 == T_STEPS - 1) {
            // final step (odd): gates + stag store only — no publish/poll/BAR
            float acc[4];
#pragma unroll
            for (int q = 0; q < 4; ++q) {
                float a = gxp[q];
#pragma unroll
                for (int i = 0; i < 4; ++i) a += dot4(whh[q * 4 + i], hr[i]);
                acc[q] = a;
            }
#pragma unroll
            for (int m = 1; m < 64; m <<= 1) {
#pragma unroll
                for (int q = 0; q < 4; ++q) acc[q] += __shfl_xor(acc[q], m, 64);
            }
            const float gi = sigmoidf_(acc[0] + bias[0]);
            const float gf = sigmoidf_(acc[1] + bias[1]);
            const float gg = tanhf_   (acc[2] + bias[2]);
            const float go = sigmoidf_(acc[3] + bias[3]);
            c = gf * c + gi * gg;
            const float hval = go * tanhf_(c);
            if (l == 0) stagb[(T_STEPS - 1) * 4 + w] = hval;
            break;
        }
        STEP_BODY(t2 + 1, xB, xA);          // odd step
    }
}

// stag[b][t][r] -> out[t][4b+r]; writes coalesced per block
__global__ __launch_bounds__(256)
void untranspose(const float* __restrict__ stag, float* __restrict__ out)
{
    const int t = blockIdx.x;
    const int b = threadIdx.x;
    f32x4 v = *(const f32x4*)(stag + (size_t)b * T_STEPS * 4 + t * 4);
    *(f32x4*)(out + (size_t)t * HDIM + 4 * b) = v;
}

extern "C" void kernel_launch(void* const* d_in, const int* in_sizes, int n_in,
                              void* d_out, int out_size, void* d_ws, size_t ws_size,
                              hipStream_t stream)
{
    const float* x    = (const float*)d_in[0];
    const float* W_ih = (const float*)d_in[1];
    const float* W_hh = (const float*)d_in[2];
    const float* b_ih = (const float*)d_in[3];
    const float* b_hh = (const float*)d_in[4];
    const float* h0   = (const float*)d_in[5];
    const float* c0   = (const float*)d_in[6];

    unsigned int* ring = (unsigned int*)d_ws;
    float* stag = (float*)((char*)d_ws + (1u << 20));

    hipMemsetAsync(d_ws, 0, 2 * NBLK * 16 * sizeof(unsigned int), stream);
    lstm_persistent<<<NBLK, NTHR, 0, stream>>>(x, W_ih, W_hh, b_ih, b_hh, h0, c0,
                                               stag, ring);
    untranspose<<<T_STEPS, 256, 0, stream>>>(stag, (float*)d_out);
}